// Round 7
// baseline (779.865 us; speedup 1.0000x reference)
//
#include <hip/hip_runtime.h>
#include <cstdint>
#include <cstddef>

#define B_   64
#define NI   2048
#define DI   16
#define NO   32
#define JD   1024          // NO*DO
#define IT   16            // capsules-in per block
#define NBX  (NI/IT)       // 128 partial slices
#define XSTR 260           // x_lds row stride (u32)
#define EPSQ 1e-9f

typedef __attribute__((ext_vector_type(8)))  short bf16x8;
typedef __attribute__((ext_vector_type(16))) float f32x16;

// truncation split: w == hi + lo + O(2^-16 w); packed (hi16<<16)|lo16
__device__ __forceinline__ uint32_t pack_split(float w) {
  uint32_t u = __float_as_uint(w);
  float hf = __uint_as_float(u & 0xffff0000u);
  uint32_t lo = __float_as_uint(w - hf) >> 16;
  return (u & 0xffff0000u) | lo;
}

__device__ __forceinline__ void cvt8(const float4 a, const float4 b, bf16x8& h8, bf16x8& l8) {
  float w[8] = {a.x, a.y, a.z, a.w, b.x, b.y, b.z, b.w};
  #pragma unroll
  for (int e = 0; e < 8; ++e) {
    uint32_t u = __float_as_uint(w[e]);
    float hf = __uint_as_float(u & 0xffff0000u);
    h8[e] = (short)(u >> 16);
    l8[e] = (short)(__float_as_uint(w[e] - hf) >> 16);
  }
}

__device__ __forceinline__ f32x16 zero16() {
  f32x16 z;
  #pragma unroll
  for (int r = 0; r < 16; ++r) z[r] = 0.0f;
  return z;
}

// Block: 512 thr = 8 waves; wave wv owns jd rows [wv*128, wv*128+128) as 4 MFMA
// 32x32 M-tiles; cols = 32 batches (blockIdx.y half). K=16=DI exact.
// u = Whi*xhi + Whi*xlo + Wlo*xhi (compensated bf16).
// ROUTE: per-i no-max softmax over j, ONE barrier per i (ping-pong al + per-lane
// denominator), u recomputed post-softmax from kept frags (VGPR relief).
template<bool ROUTE>
__global__ __launch_bounds__(512, 2)
void caps_pass(const float* __restrict__ x, const float* __restrict__ W,
               const float* __restrict__ vin, float* __restrict__ part)
{
  __shared__ uint32_t xl[32 * XSTR];   // x, packed bf16 hi|lo
  __shared__ float al[2][NO][32];      // exp(logit)  [buf][j][rot(b)]

  const int t    = threadIdx.x;
  const int wv   = t >> 6;
  const int l    = t & 63;
  const int col  = l & 31;             // output batch within half (C: col=lane&31)
  const int hb   = l >> 5;
  const int p    = blockIdx.x;
  const int half = blockIdx.y;
  const int i0   = p * IT;
  const int b0   = half * 32;

  // ---- stage x[b0..b0+31][i0..i0+15][0..15], pre-split to bf16 hi|lo ----
  for (int idx = t; idx < 32 * 64; idx += 512) {
    const int bb = idx >> 6, c4 = idx & 63;
    const float4 xv = *reinterpret_cast<const float4*>(
        x + (size_t)(b0 + bb) * (NI * DI) + (size_t)i0 * DI + (c4 << 2));
    uint4 o;
    o.x = pack_split(xv.x); o.y = pack_split(xv.y);
    o.z = pack_split(xv.z); o.w = pack_split(xv.w);
    *reinterpret_cast<uint4*>(&xl[bb * XSTR + (c4 << 2)]) = o;
  }

  // ---- v gather (fixed per lane): v[b=col][jd = wv*128 + m*32 + row(r,hb)] ----
  float vreg[4][16];
  if constexpr (ROUTE) {
    #pragma unroll
    for (int m = 0; m < 4; ++m)
      #pragma unroll
      for (int r = 0; r < 16; ++r) {
        const int row = (r & 3) + 8 * (r >> 2) + 4 * hb;
        vreg[m][r] = vin[(size_t)(b0 + col) * JD + wv * 128 + m * 32 + row];
      }
  }

  f32x16 sacc[4];
  #pragma unroll
  for (int m = 0; m < 4; ++m) sacc[m] = zero16();

  __syncthreads();

  if constexpr (!ROUTE) {
    for (int ii = 0; ii < IT; ++ii) {
      const uint4 q0 = *reinterpret_cast<const uint4*>(&xl[col * XSTR + (ii << 4) + (hb << 3)]);
      const uint4 q1 = *reinterpret_cast<const uint4*>(&xl[col * XSTR + (ii << 4) + (hb << 3) + 4]);
      bf16x8 xh, xo;
      const uint32_t qq[8] = {q0.x, q0.y, q0.z, q0.w, q1.x, q1.y, q1.z, q1.w};
      #pragma unroll
      for (int e = 0; e < 8; ++e) { xh[e] = (short)(qq[e] >> 16); xo[e] = (short)(qq[e] & 0xffff); }

      const float* wbase = W + (size_t)(i0 + ii) * (JD * DI) + (size_t)wv * 128 * DI;
      #pragma unroll
      for (int m = 0; m < 4; ++m) {
        const float* wt = wbase + m * 32 * DI + col * DI + (hb << 3);
        const float4 wa = *reinterpret_cast<const float4*>(wt);
        const float4 wb = *reinterpret_cast<const float4*>(wt + 4);
        bf16x8 wh, wl; cvt8(wa, wb, wh, wl);
        sacc[m] = __builtin_amdgcn_mfma_f32_32x32x16_bf16(wh, xh, sacc[m], 0, 0, 0);
        sacc[m] = __builtin_amdgcn_mfma_f32_32x32x16_bf16(wh, xo, sacc[m], 0, 0, 0);
        sacc[m] = __builtin_amdgcn_mfma_f32_32x32x16_bf16(wl, xh, sacc[m], 0, 0, 0);
      }
    }
  } else {
    // preload W tile for ii=0
    float4 wa[4], wb[4];
    {
      const float* wbase = W + (size_t)i0 * (JD * DI) + (size_t)wv * 128 * DI;
      #pragma unroll
      for (int m = 0; m < 4; ++m) {
        const float* wt = wbase + m * 32 * DI + col * DI + (hb << 3);
        wa[m] = *reinterpret_cast<const float4*>(wt);
        wb[m] = *reinterpret_cast<const float4*>(wt + 4);
      }
    }

    #pragma unroll 2
    for (int ii = 0; ii < IT; ++ii) {
      // B-frag from LDS
      const uint4 q0 = *reinterpret_cast<const uint4*>(&xl[col * XSTR + (ii << 4) + (hb << 3)]);
      const uint4 q1 = *reinterpret_cast<const uint4*>(&xl[col * XSTR + (ii << 4) + (hb << 3) + 4]);
      bf16x8 xh, xo;
      const uint32_t qq[8] = {q0.x, q0.y, q0.z, q0.w, q1.x, q1.y, q1.z, q1.w};
      #pragma unroll
      for (int e = 0; e < 8; ++e) { xh[e] = (short)(qq[e] >> 16); xo[e] = (short)(qq[e] & 0xffff); }

      // convert current W to frags, then prefetch next tile into wa/wb
      bf16x8 wh[4], wl[4];
      #pragma unroll
      for (int m = 0; m < 4; ++m) cvt8(wa[m], wb[m], wh[m], wl[m]);
      if (ii + 1 < IT) {
        const float* wbase = W + (size_t)(i0 + ii + 1) * (JD * DI) + (size_t)wv * 128 * DI;
        #pragma unroll
        for (int m = 0; m < 4; ++m) {
          const float* wt = wbase + m * 32 * DI + col * DI + (hb << 3);
          wa[m] = *reinterpret_cast<const float4*>(wt);
          wb[m] = *reinterpret_cast<const float4*>(wt + 4);
        }
      }

      // MFMA set 1 -> agreement logits -> exp into al (no max: |a| small, fp32-safe)
      float eo[4];
      #pragma unroll
      for (int m = 0; m < 4; ++m) {
        f32x16 u = zero16();
        u = __builtin_amdgcn_mfma_f32_32x32x16_bf16(wh[m], xh, u, 0, 0, 0);
        u = __builtin_amdgcn_mfma_f32_32x32x16_bf16(wh[m], xo, u, 0, 0, 0);
        u = __builtin_amdgcn_mfma_f32_32x32x16_bf16(wl[m], xh, u, 0, 0, 0);
        float s = 0.f;
        #pragma unroll
        for (int r = 0; r < 16; ++r) s += u[r] * vreg[m][r];
        s += __shfl_xor(s, 32);
        eo[m] = __expf(s);
      }
      if (l < 32) {
        #pragma unroll
        for (int m = 0; m < 4; ++m) {
          const int j = (wv << 2) + m;
          al[ii & 1][j][(col + j) & 31] = eo[m];   // rotation: conflict-free rd/wr
        }
      }
      __syncthreads();   // the ONLY barrier per i (ping-pong buffers al)

      // per-lane denominator: 32 conflict-free LDS reads (hb pair broadcasts)
      float den = 0.f;
      #pragma unroll
      for (int j = 0; j < 32; ++j) den += al[ii & 1][j][(col + j) & 31];
      const float rden = 1.0f / den;

      // MFMA set 2 (recompute u from kept frags) -> weighted accumulate
      #pragma unroll
      for (int m = 0; m < 4; ++m) {
        f32x16 u = zero16();
        u = __builtin_amdgcn_mfma_f32_32x32x16_bf16(wh[m], xh, u, 0, 0, 0);
        u = __builtin_amdgcn_mfma_f32_32x32x16_bf16(wh[m], xo, u, 0, 0, 0);
        u = __builtin_amdgcn_mfma_f32_32x32x16_bf16(wl[m], xh, u, 0, 0, 0);
        const float cm = eo[m] * rden;
        #pragma unroll
        for (int r = 0; r < 16; ++r) sacc[m][r] += cm * u[r];
      }
    }
  }

  // ---- epilogue: float4 stores (rows r=4g..4g+3 are consecutive jd) ----
  #pragma unroll
  for (int m = 0; m < 4; ++m)
    #pragma unroll
    for (int g = 0; g < 4; ++g) {
      const int jd = (wv << 7) + (m << 5) + (g << 3) + (hb << 2);
      *reinterpret_cast<float4*>(part + (((size_t)(p * B_ + b0 + col)) << 10) + jd) =
          make_float4(sacc[m][4 * g], sacc[m][4 * g + 1], sacc[m][4 * g + 2], sacc[m][4 * g + 3]);
    }
}

// out[b,jd] = squash_d(scale * sum_p part[p][b][jd]) [+ vprev]
// grid (64, 2), 128 thr; thread owns 4 consecutive jd (float4), 8-deep p-ILP.
__global__ void reduce_squash(const float* __restrict__ part,
                              const float* __restrict__ vprev,
                              float* __restrict__ out, float scale, int addPrev)
{
  const int b   = blockIdx.x;
  const int jd0 = blockIdx.y * 512 + threadIdx.x * 4;

  float4 acc[8];
  #pragma unroll
  for (int u = 0; u < 8; ++u) acc[u] = make_float4(0.f, 0.f, 0.f, 0.f);

  for (int p = 0; p < NBX; p += 8) {
    #pragma unroll
    for (int u = 0; u < 8; ++u) {
      const float4 v = *reinterpret_cast<const float4*>(
          part + (((size_t)((p + u) * B_ + b)) << 10) + jd0);
      acc[u].x += v.x; acc[u].y += v.y; acc[u].z += v.z; acc[u].w += v.w;
    }
  }
  #pragma unroll
  for (int u = 1; u < 8; ++u) {
    acc[0].x += acc[u].x; acc[0].y += acc[u].y;
    acc[0].z += acc[u].z; acc[0].w += acc[u].w;
  }

  float val[4] = {acc[0].x * scale, acc[0].y * scale, acc[0].z * scale, acc[0].w * scale};
  float sq = val[0]*val[0] + val[1]*val[1] + val[2]*val[2] + val[3]*val[3];
  #pragma unroll
  for (int w = 1; w < 8; w <<= 1) sq += __shfl_xor(sq, w, 8);   // 8 thr x 4 d = 32 d

  const float f = sq / ((1.0f + sq + EPSQ) * sqrtf(sq + EPSQ));
  float4 o = make_float4(f * val[0], f * val[1], f * val[2], f * val[3]);
  if (addPrev) {
    const float4 vp = *reinterpret_cast<const float4*>(vprev + (size_t)b * JD + jd0);
    o.x += vp.x; o.y += vp.y; o.z += vp.z; o.w += vp.w;
  }
  *reinterpret_cast<float4*>(out + (size_t)b * JD + jd0) = o;
}

extern "C" void kernel_launch(void* const* d_in, const int* in_sizes, int n_in,
                              void* d_out, int out_size, void* d_ws, size_t ws_size,
                              hipStream_t stream) {
  const float* x = (const float*)d_in[0];
  const float* W = (const float*)d_in[1];
  float* ws  = (float*)d_ws;
  float* out = (float*)d_out;

  float* partb = ws;                                   // [128][64][1024] = 32 MB
  float* v0    = ws + (size_t)NBX * B_ * JD;
  float* vs    = v0 + B_ * JD;

  const dim3 grid(NBX, 2);
  const dim3 rgrid(B_, 2);
  // iter 0: uniform c -> s = (1/32) sum_i u_hat
  caps_pass<false><<<grid, 512, 0, stream>>>(x, W, nullptr, partb);
  reduce_squash<<<rgrid, 128, 0, stream>>>(partb, nullptr, v0, 1.0f / 32.0f, 0);
  // iter 1: b1 = u.v0
  caps_pass<true><<<grid, 512, 0, stream>>>(x, W, v0, partb);
  reduce_squash<<<rgrid, 128, 0, stream>>>(partb, v0, vs, 1.0f, 1);
  // iter 2: b2 = u.(v0+v1)
  caps_pass<true><<<grid, 512, 0, stream>>>(x, W, vs, partb);
  reduce_squash<<<rgrid, 128, 0, stream>>>(partb, nullptr, out, 1.0f, 0);
}

// Round 8
// 324.536 us; speedup vs baseline: 2.4030x; 2.4030x over previous
//
#include <hip/hip_runtime.h>
#include <cstdint>
#include <cstddef>

#define B_   64
#define NI   2048
#define DI   16
#define NO   32
#define JD   1024          // NO*DO
#define IT   16            // capsules-in per block
#define NBX  (NI/IT)       // 128 partial slices
#define XSTR 260           // x_lds row stride (u32)
#define EPSQ 1e-9f

typedef __attribute__((ext_vector_type(8)))  short bf16x8;
typedef __attribute__((ext_vector_type(16))) float f32x16;

// truncation split: w == hi + lo + O(2^-16 w); packed (hi16<<16)|lo16
__device__ __forceinline__ uint32_t pack_split(float w) {
  uint32_t u = __float_as_uint(w);
  float hf = __uint_as_float(u & 0xffff0000u);
  uint32_t lo = __float_as_uint(w - hf) >> 16;
  return (u & 0xffff0000u) | lo;
}

__device__ __forceinline__ void cvt8(const float4 a, const float4 b, bf16x8& h8, bf16x8& l8) {
  float w[8] = {a.x, a.y, a.z, a.w, b.x, b.y, b.z, b.w};
  #pragma unroll
  for (int e = 0; e < 8; ++e) {
    uint32_t u = __float_as_uint(w[e]);
    float hf = __uint_as_float(u & 0xffff0000u);
    h8[e] = (short)(u >> 16);
    l8[e] = (short)(__float_as_uint(w[e] - hf) >> 16);
  }
}

__device__ __forceinline__ f32x16 zero16() {
  f32x16 z;
  #pragma unroll
  for (int r = 0; r < 16; ++r) z[r] = 0.0f;
  return z;
}

// Block: 512 thr = 8 waves; wave wv owns jd rows [wv*128, wv*128+128) as 4 MFMA
// 32x32 M-tiles; cols = 32 batches (blockIdx.y half). K=16=DI exact.
// u = Whi*xhi + Whi*xlo + Wlo*xhi (compensated bf16, err ~1e-4).
// ROUTE: per-i agreement a=u.v, softmax_j via LDS, s += c*u.  else: s += u.
// NOTE round-7 lesson: register W-prefetch + unroll 2 + recompute-u spilled at
// VGPR=128 (FETCH +184MB, 4x slower). This is the round-3 structure (u[] kept
// live, per-ii W loads, unroll 1) which measured ~70us/pass.
template<bool ROUTE>
__global__ __launch_bounds__(512, 2)
void caps_pass(const float* __restrict__ x, const float* __restrict__ W,
               const float* __restrict__ vin, float* __restrict__ part)
{
  __shared__ uint32_t xl[32 * XSTR];   // x, packed bf16 hi|lo
  __shared__ float al[NO * 32];        // logits  [j][rot(b)]
  __shared__ float cl[NO * 32];        // softmax [j][rot(b)]

  const int t    = threadIdx.x;
  const int wv   = t >> 6;
  const int l    = t & 63;
  const int col  = l & 31;             // output batch within half (C: col=lane&31)
  const int hb   = l >> 5;
  const int p    = blockIdx.x;
  const int half = blockIdx.y;
  const int i0   = p * IT;
  const int b0   = half * 32;

  // ---- stage x[b0..b0+31][i0..i0+15][0..15], pre-split to bf16 hi|lo ----
  for (int idx = t; idx < 32 * 64; idx += 512) {
    const int bb = idx >> 6, c4 = idx & 63;
    const float4 xv = *reinterpret_cast<const float4*>(
        x + (size_t)(b0 + bb) * (NI * DI) + (size_t)i0 * DI + (c4 << 2));
    uint4 o;
    o.x = pack_split(xv.x); o.y = pack_split(xv.y);
    o.z = pack_split(xv.z); o.w = pack_split(xv.w);
    *reinterpret_cast<uint4*>(&xl[bb * XSTR + (c4 << 2)]) = o;
  }

  // ---- v gather (fixed per lane): v[b=col][jd = wv*128 + m*32 + row(r,hb)] ----
  float vreg[4][16];
  if constexpr (ROUTE) {
    #pragma unroll
    for (int m = 0; m < 4; ++m)
      #pragma unroll
      for (int r = 0; r < 16; ++r) {
        const int row = (r & 3) + 8 * (r >> 2) + 4 * hb;
        vreg[m][r] = vin[(size_t)(b0 + col) * JD + wv * 128 + m * 32 + row];
      }
  }

  f32x16 sacc[4];
  #pragma unroll
  for (int m = 0; m < 4; ++m) sacc[m] = zero16();

  __syncthreads();

  if constexpr (!ROUTE) {
    for (int ii = 0; ii < IT; ++ii) {
      const uint4 q0 = *reinterpret_cast<const uint4*>(&xl[col * XSTR + (ii << 4) + (hb << 3)]);
      const uint4 q1 = *reinterpret_cast<const uint4*>(&xl[col * XSTR + (ii << 4) + (hb << 3) + 4]);
      bf16x8 xh, xo;
      const uint32_t qq[8] = {q0.x, q0.y, q0.z, q0.w, q1.x, q1.y, q1.z, q1.w};
      #pragma unroll
      for (int e = 0; e < 8; ++e) { xh[e] = (short)(qq[e] >> 16); xo[e] = (short)(qq[e] & 0xffff); }

      const float* wbase = W + (size_t)(i0 + ii) * (JD * DI) + (size_t)wv * 128 * DI;
      #pragma unroll
      for (int m = 0; m < 4; ++m) {
        const float* wt = wbase + m * 32 * DI + col * DI + (hb << 3);
        const float4 wa = *reinterpret_cast<const float4*>(wt);
        const float4 wb = *reinterpret_cast<const float4*>(wt + 4);
        bf16x8 wh, wl; cvt8(wa, wb, wh, wl);
        sacc[m] = __builtin_amdgcn_mfma_f32_32x32x16_bf16(wh, xh, sacc[m], 0, 0, 0);
        sacc[m] = __builtin_amdgcn_mfma_f32_32x32x16_bf16(wh, xo, sacc[m], 0, 0, 0);
        sacc[m] = __builtin_amdgcn_mfma_f32_32x32x16_bf16(wl, xh, sacc[m], 0, 0, 0);
      }
    }
  } else {
    #pragma unroll 1
    for (int ii = 0; ii < IT; ++ii) {
      const uint4 q0 = *reinterpret_cast<const uint4*>(&xl[col * XSTR + (ii << 4) + (hb << 3)]);
      const uint4 q1 = *reinterpret_cast<const uint4*>(&xl[col * XSTR + (ii << 4) + (hb << 3) + 4]);
      bf16x8 xh, xo;
      const uint32_t qq[8] = {q0.x, q0.y, q0.z, q0.w, q1.x, q1.y, q1.z, q1.w};
      #pragma unroll
      for (int e = 0; e < 8; ++e) { xh[e] = (short)(qq[e] >> 16); xo[e] = (short)(qq[e] & 0xffff); }

      const float* wbase = W + (size_t)(i0 + ii) * (JD * DI) + (size_t)wv * 128 * DI;
      f32x16 u[4];
      #pragma unroll
      for (int m = 0; m < 4; ++m) {
        const float* wt = wbase + m * 32 * DI + col * DI + (hb << 3);
        const float4 wa = *reinterpret_cast<const float4*>(wt);
        const float4 wb = *reinterpret_cast<const float4*>(wt + 4);
        bf16x8 wh, wl; cvt8(wa, wb, wh, wl);
        f32x16 c = zero16();
        c = __builtin_amdgcn_mfma_f32_32x32x16_bf16(wh, xh, c, 0, 0, 0);
        c = __builtin_amdgcn_mfma_f32_32x32x16_bf16(wh, xo, c, 0, 0, 0);
        c = __builtin_amdgcn_mfma_f32_32x32x16_bf16(wl, xh, c, 0, 0, 0);
        u[m] = c;
      }

      // agreement a[b, j=wv*4+m] = sum_d u*v ; halves l<->l+32 hold disjoint rows
      float ap[4];
      #pragma unroll
      for (int m = 0; m < 4; ++m) {
        float s = 0.f;
        #pragma unroll
        for (int r = 0; r < 16; ++r) s += u[m][r] * vreg[m][r];
        s += __shfl_xor(s, 32);
        ap[m] = s;
      }
      if (l < 32) {
        #pragma unroll
        for (int m = 0; m < 4; ++m) {
          const int j = (wv << 2) + m;
          al[(j << 5) + ((col + j) & 31)] = ap[m];   // rotation swizzle
        }
      }
      __syncthreads();

      // softmax over j (32) for 32 batches: 512 thr x 2 rounds
      {
        const int jj = t & 31;
        #pragma unroll
        for (int rd = 0; rd < 2; ++rd) {
          const int bb = (t >> 5) + (rd << 4);
          const float av = al[(jj << 5) + ((bb + jj) & 31)];
          float mx = av;
          #pragma unroll
          for (int s = 1; s < 32; s <<= 1) mx = fmaxf(mx, __shfl_xor(mx, s, 32));
          const float e = __expf(av - mx);
          float den = e;
          #pragma unroll
          for (int s = 1; s < 32; s <<= 1) den += __shfl_xor(den, s, 32);
          cl[(jj << 5) + ((bb + jj) & 31)] = e / den;
        }
      }
      __syncthreads();

      #pragma unroll
      for (int m = 0; m < 4; ++m) {
        const int j = (wv << 2) + m;
        const float cv = cl[(j << 5) + ((col + j) & 31)];
        #pragma unroll
        for (int r = 0; r < 16; ++r) sacc[m][r] += cv * u[m][r];
      }
    }
  }

  // ---- epilogue: float4 stores (rows r=4g..4g+3 are consecutive jd) ----
  #pragma unroll
  for (int m = 0; m < 4; ++m)
    #pragma unroll
    for (int g = 0; g < 4; ++g) {
      const int jd = (wv << 7) + (m << 5) + (g << 3) + (hb << 2);
      *reinterpret_cast<float4*>(part + (((size_t)(p * B_ + b0 + col)) << 10) + jd) =
          make_float4(sacc[m][4 * g], sacc[m][4 * g + 1], sacc[m][4 * g + 2], sacc[m][4 * g + 3]);
    }
}

// out[b,jd] = squash_d(scale * sum_p part[p][b][jd]) [+ vprev]
// grid (64, 2), 128 thr; thread owns 4 consecutive jd (float4), 8-deep p-ILP.
__global__ void reduce_squash(const float* __restrict__ part,
                              const float* __restrict__ vprev,
                              float* __restrict__ out, float scale, int addPrev)
{
  const int b   = blockIdx.x;
  const int jd0 = blockIdx.y * 512 + threadIdx.x * 4;

  float4 acc[8];
  #pragma unroll
  for (int u = 0; u < 8; ++u) acc[u] = make_float4(0.f, 0.f, 0.f, 0.f);

  for (int p = 0; p < NBX; p += 8) {
    #pragma unroll
    for (int u = 0; u < 8; ++u) {
      const float4 v = *reinterpret_cast<const float4*>(
          part + (((size_t)((p + u) * B_ + b)) << 10) + jd0);
      acc[u].x += v.x; acc[u].y += v.y; acc[u].z += v.z; acc[u].w += v.w;
    }
  }
  #pragma unroll
  for (int u = 1; u < 8; ++u) {
    acc[0].x += acc[u].x; acc[0].y += acc[u].y;
    acc[0].z += acc[u].z; acc[0].w += acc[u].w;
  }

  float val[4] = {acc[0].x * scale, acc[0].y * scale, acc[0].z * scale, acc[0].w * scale};
  float sq = val[0]*val[0] + val[1]*val[1] + val[2]*val[2] + val[3]*val[3];
  #pragma unroll
  for (int w = 1; w < 8; w <<= 1) sq += __shfl_xor(sq, w, 8);   // 8 thr x 4 d = 32 d

  const float f = sq / ((1.0f + sq + EPSQ) * sqrtf(sq + EPSQ));
  float4 o = make_float4(f * val[0], f * val[1], f * val[2], f * val[3]);
  if (addPrev) {
    const float4 vp = *reinterpret_cast<const float4*>(vprev + (size_t)b * JD + jd0);
    o.x += vp.x; o.y += vp.y; o.z += vp.z; o.w += vp.w;
  }
  *reinterpret_cast<float4*>(out + (size_t)b * JD + jd0) = o;
}

extern "C" void kernel_launch(void* const* d_in, const int* in_sizes, int n_in,
                              void* d_out, int out_size, void* d_ws, size_t ws_size,
                              hipStream_t stream) {
  const float* x = (const float*)d_in[0];
  const float* W = (const float*)d_in[1];
  float* ws  = (float*)d_ws;
  float* out = (float*)d_out;

  float* partb = ws;                                   // [128][64][1024] = 32 MB
  float* v0    = ws + (size_t)NBX * B_ * JD;
  float* vs    = v0 + B_ * JD;

  const dim3 grid(NBX, 2);
  const dim3 rgrid(B_, 2);
  // iter 0: uniform c -> s = (1/32) sum_i u_hat
  caps_pass<false><<<grid, 512, 0, stream>>>(x, W, nullptr, partb);
  reduce_squash<<<rgrid, 128, 0, stream>>>(partb, nullptr, v0, 1.0f / 32.0f, 0);
  // iter 1: b1 = u.v0
  caps_pass<true><<<grid, 512, 0, stream>>>(x, W, v0, partb);
  reduce_squash<<<rgrid, 128, 0, stream>>>(partb, v0, vs, 1.0f, 1);
  // iter 2: b2 = u.(v0+v1)
  caps_pass<true><<<grid, 512, 0, stream>>>(x, W, vs, partb);
  reduce_squash<<<rgrid, 128, 0, stream>>>(partb, nullptr, out, 1.0f, 0);
}